// Round 18
// baseline (853.774 us; speedup 1.0000x reference)
//
#include <hip/hip_runtime.h>
#include <math.h>

#define NL    8
#define CCH   128
#define CINC  80
#define CPAD  128
#define HH    16
#define WW    4096
#define HW    (HH*WW)
#define PADW  128
#define WWP   (WW + 2*PADW)
#define NT    10            // K-steps: 8 off-center taps, cond (t=7), center tap LAST (t=9)
#define PADF  64            // f32 row stride for sres transpose (128*64*4 = 32KB exactly)

// workspace element counts (~144 MB)
#define HBF_N   (2*HH*WWP*CCH)        // u16 (per buffer)
#define ZROW_N  (WWP*CCH)             // u16
#define CT_N    (2*HW*CPAD)           // u16
#define SKB_N   (2*HW*CCH)            // u16 bf16 skip accumulator, plane-major [b][c][y][x]
#define GW_N    (NL*NT*4*16*64*8)     // u16
#define RW_N    (NL*4*16*64*8)        // u16

using v8s   = __attribute__((ext_vector_type(8))) short;
using f32x4 = __attribute__((ext_vector_type(4))) float;

__device__ __forceinline__ unsigned short f2bf(float f) {
    unsigned int u = __builtin_bit_cast(unsigned int, f);
    u += 0x7fffu + ((u >> 16) & 1u);
    return (unsigned short)(u >> 16);
}
__device__ __forceinline__ float bfu2f(unsigned int v) {
    return __builtin_bit_cast(float, v << 16);
}
// fast gated activation: tanh(a)*sigmoid(g) via v_exp + v_rcp
__device__ __forceinline__ float gated(float a, float g) {
    float ac = fminf(a, 15.0f);
    float e  = __expf(2.0f * ac);
    float th = (e - 1.0f) * __builtin_amdgcn_rcpf(e + 1.0f);
    float sg = __builtin_amdgcn_rcpf(1.0f + __expf(-g));
    return th * sg;
}

__device__ __forceinline__ void gl_lds16(const void* g, void* l) {
    __builtin_amdgcn_global_load_lds(
        (const __attribute__((address_space(1))) unsigned int*)g,
        (__attribute__((address_space(3))) unsigned int*)l, 16, 0, 0);
}

// position t (0..9) -> source: t<7 -> tap t; t==7 -> cond; t==8 -> tap 8; t==9 -> tap 7 (center)
__device__ __host__ __forceinline__ int tap_of(int t) { return (t < 7) ? t : (t == 8 ? 8 : 7); }

// ---------- one-time weight swizzle into MFMA A-fragment order ----------
__global__ void prep_weights(const float* __restrict__ fg_w, const float* __restrict__ fgc_w,
                             const float* __restrict__ rs_w,
                             const float* __restrict__ fg_b, const float* __restrict__ fgc_b,
                             const float* __restrict__ rs_b,
                             unsigned short* __restrict__ gw, unsigned short* __restrict__ rw,
                             float* __restrict__ gbias, float* __restrict__ rbias) {
    const int total = GW_N + RW_N + 2 * NL * 256;
    const int stride = gridDim.x * blockDim.x;
    for (int idx = blockIdx.x * blockDim.x + threadIdx.x; idx < total; idx += stride) {
        if (idx < GW_N) {
            int t0 = idx;
            int j = t0 & 7;  t0 >>= 3;
            int l = t0 & 63; t0 >>= 6;
            int mt = t0 & 15; t0 >>= 4;
            int tq = t0 % (NT*4);
            int i  = t0 / (NT*4);
            int t  = tq >> 2, q = tq & 3;
            int m  = mt*16 + (l & 15);
            int oo = (m & 1)*128 + (m >> 1);
            int ci = q*32 + 8*(l >> 4) + j;
            float v;
            if (t == 7) {
                v = (ci < CINC) ? fgc_w[((size_t)i*256 + oo)*CINC + ci] : 0.0f;
            } else {
                int tt = tap_of(t);
                v = fg_w[(((size_t)i*256 + oo)*128 + ci)*9 + tt];   // tt == kh*3+kw
            }
            gw[idx] = f2bf(v);
        } else if (idx < GW_N + RW_N) {
            int t0 = idx - GW_N;
            int j = t0 & 7;  t0 >>= 3;
            int l = t0 & 63; t0 >>= 6;
            int mt = t0 & 15; t0 >>= 4;
            int q = t0 & 3;
            int i = t0 >> 2;
            int m  = mt*16 + (l & 15);
            int oo = (m & 1)*128 + (m >> 1);
            int ci = q*32 + 8*(l >> 4) + j;
            rw[idx - GW_N] = f2bf(rs_w[((size_t)i*256 + oo)*128 + ci]);
        } else {
            int t0 = idx - GW_N - RW_N;
            if (t0 < NL*256) {
                int i = t0 >> 8, m = t0 & 255;
                int oo = (m & 1)*128 + (m >> 1);
                gbias[t0] = fg_b[i*256 + oo] + fgc_b[i*256 + oo];
            } else {
                t0 -= NL*256;
                int i = t0 >> 8, m = t0 & 255;
                int oo = (m & 1)*128 + (m >> 1);
                rbias[t0] = rs_b[i*256 + oo];
            }
        }
    }
}

// ---------- front 1x1 conv: padded bf16 h buf0; zero buf1 pads/zrow ----------
__global__ void front_kernel(const float* __restrict__ xsrc,
                             const float* __restrict__ fw, const float* __restrict__ fb,
                             unsigned short* __restrict__ hbf0,
                             unsigned short* __restrict__ hbf1, unsigned short* __restrict__ zrow) {
    const int stride = gridDim.x * blockDim.x;
    const int t0 = blockIdx.x * blockDim.x + threadIdx.x;
    for (int idx = t0; idx < HBF_N; idx += stride) {
        int c = idx & 127;
        int rest = idx >> 7;
        int xp = rest % WWP; rest /= WWP;
        int y = rest & 15;
        int b = rest >> 4;
        int x = xp - PADW;
        if (x >= 0 && x < WW)
            hbf0[idx] = f2bf(fw[c] * xsrc[((size_t)(b*HH + y))*WW + x] + fb[c]);
        else
            hbf0[idx] = 0;
    }
    const int PADN = 2*HH*2*PADW*CCH;
    for (int idx = t0; idx < PADN; idx += stride) {
        int c = idx & 127;
        int r = idx >> 7;
        int xo = r % (2*PADW); r /= (2*PADW);
        int y = r & 15;
        int b = r >> 4;
        int xp = (xo < PADW) ? xo : xo + WW;
        hbf1[(((size_t)(b*HH + y))*WWP + xp)*CCH + c] = 0;
    }
    for (int idx = t0; idx < ZROW_N; idx += stride) zrow[idx] = 0;
}

// ---------- conditioning transpose ----------
__global__ __launch_bounds__(256) void cond_transpose(const float* __restrict__ cin,
                                                      unsigned short* __restrict__ cT) {
    __shared__ unsigned short lt[CINC][72];
    const int tid = threadIdx.x, lane = tid & 63, w = tid >> 6;
    const int x0 = blockIdx.x * 64, y = blockIdx.y, b = blockIdx.z;
#pragma unroll
    for (int r = 0; r < 20; ++r) {
        int ci = w*20 + r;
        float v = cin[(((size_t)(b*CINC + ci))*HH + y)*WW + x0 + lane];
        lt[ci][lane] = f2bf(v);
    }
    __syncthreads();
    const int px = tid & 63, cg = tid >> 6;
    unsigned int pk[16];
#pragma unroll
    for (int kk = 0; kk < 16; ++kk) {
        int c0 = cg*32 + kk*2;
        unsigned int lo = (c0     < CINC) ? lt[c0][px]     : 0;
        unsigned int hi = (c0 + 1 < CINC) ? lt[c0 + 1][px] : 0;
        pk[kk] = lo | (hi << 16);
    }
    unsigned short* dst = cT + (((size_t)(b*HH + y))*WW + x0 + px)*CPAD + cg*32;
#pragma unroll
    for (int u = 0; u < 4; ++u)
        *(uint4*)(dst + u*8) = make_uint4(pk[u*4], pk[u*4+1], pk[u*4+2], pk[u*4+3]);
}

// ---------- fused layer: 8 waves x m32 tile; all-4q A-frags held across steps ----------
// Issue order per step: [vmcnt(8); barrier] stage(t+1); 4x{dsread(q); 8 MFMA; loadA(t+1,q)}.
// A(t,q) consumed from registers loaded LAST iteration -> stage gets a full step of latency cover.
__global__ __launch_bounds__(512, 4) void layer_fused(
        const unsigned short* __restrict__ hin, unsigned short* __restrict__ hout,
        const unsigned short* __restrict__ zrow, const unsigned short* __restrict__ cT,
        const unsigned short* __restrict__ gw, const float* __restrict__ gbias,
        const unsigned short* __restrict__ rw, const float* __restrict__ rbias,
        unsigned short* __restrict__ skipbf, float* __restrict__ outp,
        int layer, int dh, int dw, int first) {
    __shared__ char sbuf[2 * 16384];            // 2-buffer staging; buf0=sact, buf1 keeps h_old; both=sres

    const int tid = threadIdx.x, lane = tid & 63, w = tid >> 6;   // w in 0..7
    const int lrow = lane & 15, lk = lane >> 4;

    // XCD-aware swizzle (bijective: 2048 blocks, 8 XCDs)
    const int lin = blockIdx.x + 64*(blockIdx.y + 16*blockIdx.z);
    const int logical = (lin & 7)*256 + (lin >> 3);
    const int x0 = (logical & 63) * 64;
    const int y  = (logical >> 6) & 15;
    const int b  = logical >> 10;

    f32x4 acc[2][4];
#pragma unroll
    for (int mf = 0; mf < 2; ++mf)
#pragma unroll
        for (int nf = 0; nf < 4; ++nf) acc[mf][nf] = (f32x4){0.f, 0.f, 0.f, 0.f};

    const unsigned short* rowb[3];
#pragma unroll
    for (int kh = 0; kh < 3; ++kh) {
        int yin = y - (2 - kh)*dh;
        rowb[kh] = (yin >= 0) ? hin + ((size_t)(b*HH + yin))*WWP*CCH : zrow;
    }
    const char* cb = (const char*)(cT + (((size_t)(b*HH + y))*WW + x0)*CPAD);
    // wave w owns m-tiles mt = w*2 + mf
    const unsigned short* gwl = gw + (((size_t)layer*NT*4*16) + w*2)*512 + lane*8;

    auto stage_t = [&](int t) {
        const char* src;
        if (t == 7) src = cb;
        else {
            int tt = tap_of(t);
            int kh = tt / 3, kw = tt - kh*3;
            src = (const char*)(rowb[kh] + (size_t)(x0 + (kw - 1)*dw + PADW)*CCH);
        }
        char* dst = sbuf + (t & 1)*16384;
#pragma unroll
        for (int s = 0; s < 2; ++s) {
            unsigned o = (unsigned)(w*2 + s)*1024 + (unsigned)lane*16;
            unsigned g = o ^ (((o >> 8) & 7) << 4);
            gl_lds16(src + g, dst + (w*2 + s)*1024);
        }
    };
    auto dsread = [&](const char* bb, int q, v8s (&bv)[4]) {
#pragma unroll
        for (int nf = 0; nf < 4; ++nf) {
            int px = nf*16 + lrow;
            int o = px*256 + ((q*64 + lk*16) ^ ((lrow & 7) << 4));
            bv[nf] = *(const v8s*)(bb + o);
        }
    };
    auto mf8 = [&](v8s (&av)[2], v8s (&bv)[4]) {
        __builtin_amdgcn_s_setprio(1);
#pragma unroll
        for (int mf = 0; mf < 2; ++mf)
#pragma unroll
            for (int nf = 0; nf < 4; ++nf)
                acc[mf][nf] = __builtin_amdgcn_mfma_f32_16x16x32_bf16(av[mf], bv[nf], acc[mf][nf], 0, 0, 0);
        __builtin_amdgcn_s_setprio(0);
    };

    // ---- K-loop: all-4q A-frags resident; stage/A streams ordered for full-step cover ----
    v8s av[4][2], bv[4];
    stage_t(0);
#pragma unroll
    for (int q = 0; q < 4; ++q)
#pragma unroll
        for (int mf = 0; mf < 2; ++mf)
            av[q][mf] = *(const v8s*)(gwl + (size_t)(0*4 + q)*16*512 + mf*512);
#pragma unroll
    for (int t = 0; t < NT; ++t) {
        // outstanding: stage(t) x2 (oldest) + A(t,0..3) x8 (newest) -> wait stage(t) landed
        asm volatile("s_waitcnt vmcnt(8)" ::: "memory");
        __builtin_amdgcn_sched_barrier(0);
        __builtin_amdgcn_s_barrier();       // WAR: all waves done reading buf[(t+1)&1]
        __builtin_amdgcn_sched_barrier(0);
        if (t + 1 < NT) stage_t(t + 1);
        const char* bb = sbuf + (t & 1)*16384;
#pragma unroll
        for (int q = 0; q < 4; ++q) {
            dsread(bb, q, bv);
            mf8(av[q], bv);
            if (t + 1 < NT) {
#pragma unroll
                for (int mf = 0; mf < 2; ++mf)
                    av[q][mf] = *(const v8s*)(gwl + (size_t)((t+1)*4 + q)*16*512 + mf*512);
            }
        }
    }
    // buf1 now holds the center-tap tile == h_old (t=9 staged there, nothing after)

    // ---- gated activation -> sact LDS (buf0) ----
    char* sact = sbuf;
    const float* gb = gbias + layer*256;
#pragma unroll
    for (int mf = 0; mf < 2; ++mf) {
        int m0 = w*32 + mf*16 + lk*4;
        int c0 = m0 >> 1;                     // even
        float bF0 = gb[m0], bG0 = gb[m0+1], bF1 = gb[m0+2], bG1 = gb[m0+3];
#pragma unroll
        for (int nf = 0; nf < 4; ++nf) {
            int px = nf*16 + lrow;
            float o0 = gated(acc[mf][nf][0] + bF0, acc[mf][nf][1] + bG0);
            float o1 = gated(acc[mf][nf][2] + bF1, acc[mf][nf][3] + bG1);
            unsigned int pk = (unsigned int)f2bf(o0) | ((unsigned int)f2bf(o1) << 16);
            int byte = px*256 + c0*2;
            byte ^= (px & 7) << 4;
            *(unsigned int*)(sact + byte) = pk;
        }
    }
    // reuse acc as the res/skip accumulator
#pragma unroll
    for (int mf = 0; mf < 2; ++mf)
#pragma unroll
        for (int nf = 0; nf < 4; ++nf) acc[mf][nf] = (f32x4){0.f, 0.f, 0.f, 0.f};
    __syncthreads();

    // ---- res/skip 1x1 GEMM from sact ----
    const unsigned short* rwl = rw + (((size_t)layer*4*16) + w*2)*512 + lane*8;
#pragma unroll
    for (int q = 0; q < 4; ++q) {
        v8s a2[2];
#pragma unroll
        for (int mf = 0; mf < 2; ++mf) a2[mf] = *(const v8s*)(rwl + (size_t)(q*16 + mf)*512);
        dsread(sact, q, bv);
        mf8(a2, bv);
    }

    // ---- read h_old pairs from buf1 (before sres overwrites it) ----
    unsigned int hold[2][4];
    if (layer < NL - 1) {
#pragma unroll
        for (int mf = 0; mf < 2; ++mf) {
            int c0 = w*16 + mf*8 + lk*2;
#pragma unroll
            for (int nf = 0; nf < 4; ++nf) {
                int px = nf*16 + lrow;
                int o = px*256 + ((c0*2) ^ ((px & 7) << 4));
                hold[mf][nf] = *(const unsigned int*)(sbuf + 16384 + o);
            }
        }
    }
    __syncthreads();                          // all sact/buf1 reads done before sres overwrite

    float* sresf = (float*)sbuf;              // f32 [128][64], 32 KB, column-XOR swizzled
    const int cp = tid >> 4, xg = tid & 15;   // cp 0..31
    const int pxl = tid & 63, cg = tid >> 6;  // cg 0..7

    if (layer < NL - 1) {
        // ---- transpose h_new = h_old + res + bias -> sres[c][px^s] (fp32) ----
#pragma unroll
        for (int mf = 0; mf < 2; ++mf) {
            int c0 = w*16 + mf*8 + lk*2;
            float bR0 = rbias[layer*256 + 2*c0];
            float bR1 = rbias[layer*256 + 2*(c0 + 1)];
#pragma unroll
            for (int nf = 0; nf < 4; ++nf) {
                int px = nf*16 + lrow;
                int sw = px ^ (((c0 >> 1) & 3) << 3);
                float h0 = bfu2f(hold[mf][nf] & 0xffffu);
                float h1 = __builtin_bit_cast(float, hold[mf][nf] & 0xffff0000u);
                sresf[(c0    )*PADF + sw] = h0 + acc[mf][nf][0] + bR0;
                sresf[(c0 + 1)*PADF + sw] = h1 + acc[mf][nf][2] + bR1;
            }
        }
        __syncthreads();
        // ---- bf16 pack h_new [px][c] -> hout (coalesced); cg handles 16 channels ----
        {
            unsigned int pk3[8];
#pragma unroll
            for (int j = 0; j < 8; ++j) {
                int c0 = cg*16 + 2*j;
                int sw = pxl ^ (((c0 >> 1) & 3) << 3);    // == pxl ^ ((j&3)<<3)
                float lo = sresf[(c0    )*PADF + sw];
                float hi = sresf[(c0 + 1)*PADF + sw];
                pk3[j] = (unsigned int)f2bf(lo) | ((unsigned int)f2bf(hi) << 16);
            }
            unsigned short* hrow = hout + (((size_t)(b*HH + y))*WWP + x0 + pxl + PADW)*CCH + cg*16;
#pragma unroll
            for (int u = 0; u < 2; ++u)
                *(uint4*)(hrow + u*8) = make_uint4(pk3[u*4], pk3[u*4+1], pk3[u*4+2], pk3[u*4+3]);
        }
        __syncthreads();
    }

    // ---- skip half: transpose -> sres (same column swizzle) ----
#pragma unroll
    for (int mf = 0; mf < 2; ++mf) {
        int c0 = w*16 + mf*8 + lk*2;
#pragma unroll
        for (int nf = 0; nf < 4; ++nf) {
            int px = nf*16 + lrow;
            int sw = px ^ (((c0 >> 1) & 3) << 3);
            sresf[(c0    )*PADF + sw] = acc[mf][nf][1];
            sresf[(c0 + 1)*PADF + sw] = acc[mf][nf][3];
        }
    }
    __syncthreads();
    // ---- skip accumulate: layers 0-6 RMW bf16 skipbf; layer 7 writes fp32 d_out ----
    // LDS col (xg*4)^s holds pixel xg*4 -> GLOBAL address uses plain xg*4.
#pragma unroll
    for (int it = 0; it < 4; ++it) {
        int cc = it*32 + cp;
        int sw = ((cp >> 1) & 3) << 3;                    // (cc>>1)&3 == (cp>>1)&3
        float4 s = *(float4*)(sresf + cc*PADF + ((xg*4) ^ sw));
        float bb2 = rbias[layer*256 + 2*cc + 1];
        s.x += bb2; s.y += bb2; s.z += bb2; s.w += bb2;
        size_t p = (((size_t)(b*CCH + cc))*HH + y)*WW + x0 + xg*4;
        if (layer == NL - 1) {
            uint2 o = *(const uint2*)(skipbf + p);
            float4 r;
            r.x = s.x + bfu2f(o.x & 0xffffu);
            r.y = s.y + bfu2f(o.x >> 16);
            r.z = s.z + bfu2f(o.y & 0xffffu);
            r.w = s.w + bfu2f(o.y >> 16);
            *(float4*)(outp + p) = r;
        } else {
            if (!first) {
                uint2 o = *(const uint2*)(skipbf + p);
                s.x += bfu2f(o.x & 0xffffu);
                s.y += bfu2f(o.x >> 16);
                s.z += bfu2f(o.y & 0xffffu);
                s.w += bfu2f(o.y >> 16);
            }
            uint2 np;
            np.x = (unsigned int)f2bf(s.x) | ((unsigned int)f2bf(s.y) << 16);
            np.y = (unsigned int)f2bf(s.z) | ((unsigned int)f2bf(s.w) << 16);
            *(uint2*)(skipbf + p) = np;
        }
    }
}

extern "C" void kernel_launch(void* const* d_in, const int* in_sizes, int n_in,
                              void* d_out, int out_size, void* d_ws, size_t ws_size,
                              hipStream_t stream) {
    const float* x       = (const float*)d_in[0];
    const float* c       = (const float*)d_in[1];
    const float* front_w = (const float*)d_in[2];
    const float* front_b = (const float*)d_in[3];
    const float* fg_w    = (const float*)d_in[4];
    const float* fg_b    = (const float*)d_in[5];
    const float* fgc_w   = (const float*)d_in[6];
    const float* fgc_b   = (const float*)d_in[7];
    const float* rs_w    = (const float*)d_in[8];
    const float* rs_b    = (const float*)d_in[9];

    char* ws = (char*)d_ws;
    unsigned short* hbf0 = (unsigned short*)ws;     ws += (size_t)HBF_N * 2;
    unsigned short* hbf1 = (unsigned short*)ws;     ws += (size_t)HBF_N * 2;
    unsigned short* zrow = (unsigned short*)ws;     ws += (size_t)ZROW_N * 2;
    unsigned short* cT   = (unsigned short*)ws;     ws += (size_t)CT_N * 2;
    unsigned short* skbf = (unsigned short*)ws;     ws += (size_t)SKB_N * 2;
    unsigned short* gw   = (unsigned short*)ws;     ws += (size_t)GW_N * 2;
    unsigned short* rwq  = (unsigned short*)ws;     ws += (size_t)RW_N * 2;
    float* gbias  = (float*)ws;                     ws += (size_t)NL * 256 * 4;
    float* rbias  = (float*)ws;

    float* outp = (float*)d_out;

    prep_weights<<<2048, 256, 0, stream>>>(fg_w, fgc_w, rs_w, fg_b, fgc_b, rs_b,
                                           gw, rwq, gbias, rbias);
    front_kernel<<<2048, 256, 0, stream>>>(x, front_w, front_b, hbf0, hbf1, zrow);
    cond_transpose<<<dim3(64, 16, 2), 256, 0, stream>>>(c, cT);

    static const int DILH[NL] = {1, 2, 4, 8, 1, 2, 4, 8};
    static const int DILW[NL] = {1, 2, 4, 8, 16, 32, 64, 128};

    for (int i = 0; i < NL; ++i) {
        const unsigned short* hin = (i & 1) ? hbf1 : hbf0;
        unsigned short*       hout= (i & 1) ? hbf0 : hbf1;
        layer_fused<<<dim3(64, 16, 2), 512, 0, stream>>>(hin, hout, zrow, cT, gw, gbias,
                                                         rwq, rbias, skbf, outp,
                                                         i, DILH[i], DILW[i], i == 0 ? 1 : 0);
    }
}

// Round 19
// 829.647 us; speedup vs baseline: 1.0291x; 1.0291x over previous
//
#include <hip/hip_runtime.h>
#include <math.h>

#define NL    8
#define CCH   128
#define CINC  80
#define CPAD  128
#define HH    16
#define WW    4096
#define HW    (HH*WW)
#define PADW  128
#define WWP   (WW + 2*PADW)
#define NT    10            // K-steps: 8 off-center taps, cond (t=7), center tap LAST (t=9)
#define PADF  64            // f32 row stride for sres transpose (128*64*4 = 32KB exactly)

// workspace element counts (~144 MB)
#define HBF_N   (2*HH*WWP*CCH)        // u16 (per buffer)
#define ZROW_N  (WWP*CCH)             // u16
#define CT_N    (2*HW*CPAD)           // u16
#define SKB_N   (2*HW*CCH)            // u16 bf16 skip accumulator, plane-major [b][c][y][x]
#define GW_N    (NL*NT*4*16*64*8)     // u16
#define RW_N    (NL*4*16*64*8)        // u16

using v8s   = __attribute__((ext_vector_type(8))) short;
using f32x4 = __attribute__((ext_vector_type(4))) float;

__device__ __forceinline__ unsigned short f2bf(float f) {
    unsigned int u = __builtin_bit_cast(unsigned int, f);
    u += 0x7fffu + ((u >> 16) & 1u);
    return (unsigned short)(u >> 16);
}
__device__ __forceinline__ float bfu2f(unsigned int v) {
    return __builtin_bit_cast(float, v << 16);
}
// fast gated activation: tanh(a)*sigmoid(g) via v_exp + v_rcp
__device__ __forceinline__ float gated(float a, float g) {
    float ac = fminf(a, 15.0f);                       // tanh(15) == 1 to fp32; avoids inf/inf
    float e  = __expf(2.0f * ac);
    float th = (e - 1.0f) * __builtin_amdgcn_rcpf(e + 1.0f);
    float sg = __builtin_amdgcn_rcpf(1.0f + __expf(-g));
    return th * sg;
}

__device__ __forceinline__ void gl_lds16(const void* g, void* l) {
    __builtin_amdgcn_global_load_lds(
        (const __attribute__((address_space(1))) unsigned int*)g,
        (__attribute__((address_space(3))) unsigned int*)l, 16, 0, 0);
}

// position t (0..9) -> source: t<7 -> tap t; t==7 -> cond; t==8 -> tap 8; t==9 -> tap 7 (center)
__device__ __host__ __forceinline__ int tap_of(int t) { return (t < 7) ? t : (t == 8 ? 8 : 7); }

// ---------- one-time weight swizzle into MFMA A-fragment order ----------
__global__ void prep_weights(const float* __restrict__ fg_w, const float* __restrict__ fgc_w,
                             const float* __restrict__ rs_w,
                             const float* __restrict__ fg_b, const float* __restrict__ fgc_b,
                             const float* __restrict__ rs_b,
                             unsigned short* __restrict__ gw, unsigned short* __restrict__ rw,
                             float* __restrict__ gbias, float* __restrict__ rbias) {
    const int total = GW_N + RW_N + 2 * NL * 256;
    const int stride = gridDim.x * blockDim.x;
    for (int idx = blockIdx.x * blockDim.x + threadIdx.x; idx < total; idx += stride) {
        if (idx < GW_N) {
            int t0 = idx;
            int j = t0 & 7;  t0 >>= 3;
            int l = t0 & 63; t0 >>= 6;
            int mt = t0 & 15; t0 >>= 4;
            int tq = t0 % (NT*4);
            int i  = t0 / (NT*4);
            int t  = tq >> 2, q = tq & 3;
            int m  = mt*16 + (l & 15);
            int oo = (m & 1)*128 + (m >> 1);
            int ci = q*32 + 8*(l >> 4) + j;
            float v;
            if (t == 7) {
                v = (ci < CINC) ? fgc_w[((size_t)i*256 + oo)*CINC + ci] : 0.0f;
            } else {
                int tt = tap_of(t);
                v = fg_w[(((size_t)i*256 + oo)*128 + ci)*9 + tt];   // tt == kh*3+kw
            }
            gw[idx] = f2bf(v);
        } else if (idx < GW_N + RW_N) {
            int t0 = idx - GW_N;
            int j = t0 & 7;  t0 >>= 3;
            int l = t0 & 63; t0 >>= 6;
            int mt = t0 & 15; t0 >>= 4;
            int q = t0 & 3;
            int i = t0 >> 2;
            int m  = mt*16 + (l & 15);
            int oo = (m & 1)*128 + (m >> 1);
            int ci = q*32 + 8*(l >> 4) + j;
            rw[idx - GW_N] = f2bf(rs_w[((size_t)i*256 + oo)*128 + ci]);
        } else {
            int t0 = idx - GW_N - RW_N;
            if (t0 < NL*256) {
                int i = t0 >> 8, m = t0 & 255;
                int oo = (m & 1)*128 + (m >> 1);
                gbias[t0] = fg_b[i*256 + oo] + fgc_b[i*256 + oo];
            } else {
                t0 -= NL*256;
                int i = t0 >> 8, m = t0 & 255;
                int oo = (m & 1)*128 + (m >> 1);
                rbias[t0] = rs_b[i*256 + oo];
            }
        }
    }
}

// ---------- front 1x1 conv: padded bf16 h buf0; zero buf1 pads/zrow ----------
__global__ void front_kernel(const float* __restrict__ xsrc,
                             const float* __restrict__ fw, const float* __restrict__ fb,
                             unsigned short* __restrict__ hbf0,
                             unsigned short* __restrict__ hbf1, unsigned short* __restrict__ zrow) {
    const int stride = gridDim.x * blockDim.x;
    const int t0 = blockIdx.x * blockDim.x + threadIdx.x;
    for (int idx = t0; idx < HBF_N; idx += stride) {
        int c = idx & 127;
        int rest = idx >> 7;
        int xp = rest % WWP; rest /= WWP;
        int y = rest & 15;
        int b = rest >> 4;
        int x = xp - PADW;
        if (x >= 0 && x < WW)
            hbf0[idx] = f2bf(fw[c] * xsrc[((size_t)(b*HH + y))*WW + x] + fb[c]);
        else
            hbf0[idx] = 0;
    }
    const int PADN = 2*HH*2*PADW*CCH;
    for (int idx = t0; idx < PADN; idx += stride) {
        int c = idx & 127;
        int r = idx >> 7;
        int xo = r % (2*PADW); r /= (2*PADW);
        int y = r & 15;
        int b = r >> 4;
        int xp = (xo < PADW) ? xo : xo + WW;
        hbf1[(((size_t)(b*HH + y))*WWP + xp)*CCH + c] = 0;
    }
    for (int idx = t0; idx < ZROW_N; idx += stride) zrow[idx] = 0;
}

// ---------- conditioning transpose ----------
__global__ __launch_bounds__(256) void cond_transpose(const float* __restrict__ cin,
                                                      unsigned short* __restrict__ cT) {
    __shared__ unsigned short lt[CINC][72];
    const int tid = threadIdx.x, lane = tid & 63, w = tid >> 6;
    const int x0 = blockIdx.x * 64, y = blockIdx.y, b = blockIdx.z;
#pragma unroll
    for (int r = 0; r < 20; ++r) {
        int ci = w*20 + r;
        float v = cin[(((size_t)(b*CINC + ci))*HH + y)*WW + x0 + lane];
        lt[ci][lane] = f2bf(v);
    }
    __syncthreads();
    const int px = tid & 63, cg = tid >> 6;
    unsigned int pk[16];
#pragma unroll
    for (int kk = 0; kk < 16; ++kk) {
        int c0 = cg*32 + kk*2;
        unsigned int lo = (c0     < CINC) ? lt[c0][px]     : 0;
        unsigned int hi = (c0 + 1 < CINC) ? lt[c0 + 1][px] : 0;
        pk[kk] = lo | (hi << 16);
    }
    unsigned short* dst = cT + (((size_t)(b*HH + y))*WW + x0 + px)*CPAD + cg*32;
#pragma unroll
    for (int u = 0; u < 4; ++u)
        *(uint4*)(dst + u*8) = make_uint4(pk[u*4], pk[u*4+1], pk[u*4+2], pk[u*4+3]);
}

// ---------- fused layer: bf16 h + bf16 skip accumulator; layer 7 emits fp32 d_out ----------
// (R13, proven 831us total) 4 waves, 2-buffer counted-vmcnt staging, 2-deep A pipeline.
__global__ __launch_bounds__(256, 4) void layer_fused(
        const unsigned short* __restrict__ hin, unsigned short* __restrict__ hout,
        const unsigned short* __restrict__ zrow, const unsigned short* __restrict__ cT,
        const unsigned short* __restrict__ gw, const float* __restrict__ gbias,
        const unsigned short* __restrict__ rw, const float* __restrict__ rbias,
        unsigned short* __restrict__ skipbf, float* __restrict__ outp,
        int layer, int dh, int dw, int first) {
    __shared__ char sbuf[2 * 16384];            // 2-buffer staging; buf0=sact, buf1 keeps h_old; both=sres

    const int tid = threadIdx.x, lane = tid & 63, w = tid >> 6;
    const int lrow = lane & 15, lk = lane >> 4;

    // XCD-aware swizzle (bijective: 2048 blocks, 8 XCDs)
    const int lin = blockIdx.x + 64*(blockIdx.y + 16*blockIdx.z);
    const int logical = (lin & 7)*256 + (lin >> 3);
    const int x0 = (logical & 63) * 64;
    const int y  = (logical >> 6) & 15;
    const int b  = logical >> 10;

    f32x4 acc[4][4];
#pragma unroll
    for (int mf = 0; mf < 4; ++mf)
#pragma unroll
        for (int nf = 0; nf < 4; ++nf) acc[mf][nf] = (f32x4){0.f, 0.f, 0.f, 0.f};

    const unsigned short* rowb[3];
#pragma unroll
    for (int kh = 0; kh < 3; ++kh) {
        int yin = y - (2 - kh)*dh;
        rowb[kh] = (yin >= 0) ? hin + ((size_t)(b*HH + yin))*WWP*CCH : zrow;
    }
    const char* cb = (const char*)(cT + (((size_t)(b*HH + y))*WW + x0)*CPAD);
    const unsigned short* gwl = gw + (((size_t)layer*NT*4*16) + w*4)*512 + lane*8;

    auto stage = [&](char* dst, const char* src) {
#pragma unroll
        for (int s = 0; s < 4; ++s) {
            unsigned o = (unsigned)(w*4 + s)*1024 + (unsigned)lane*16;
            unsigned g = o ^ (((o >> 8) & 7) << 4);
            gl_lds16(src + g, dst + (w*4 + s)*1024);
        }
    };
    auto stage_t = [&](int t) {
        const char* src;
        if (t == 7) src = cb;
        else {
            int tt = tap_of(t);
            int kh = tt / 3, kw = tt - kh*3;
            src = (const char*)(rowb[kh] + (size_t)(x0 + (kw - 1)*dw + PADW)*CCH);
        }
        stage(sbuf + (t & 1)*16384, src);
    };
    auto dsread = [&](const char* bb, int q, v8s (&bv)[4]) {
#pragma unroll
        for (int nf = 0; nf < 4; ++nf) {
            int px = nf*16 + lrow;
            int o = px*256 + ((q*64 + lk*16) ^ ((lrow & 7) << 4));
            bv[nf] = *(const v8s*)(bb + o);
        }
    };
    auto loadA = [&](int t, int q, v8s (&av)[4]) {
        const unsigned short* gq = gwl + (size_t)(t*4 + q)*16*512;
#pragma unroll
        for (int mf = 0; mf < 4; ++mf) av[mf] = *(const v8s*)(gq + mf*512);
    };
    auto mf16 = [&](v8s (&av)[4], v8s (&bv)[4]) {
        __builtin_amdgcn_s_setprio(1);
#pragma unroll
        for (int mf = 0; mf < 4; ++mf)
#pragma unroll
            for (int nf = 0; nf < 4; ++nf)
                acc[mf][nf] = __builtin_amdgcn_mfma_f32_16x16x32_bf16(av[mf], bv[nf], acc[mf][nf], 0, 0, 0);
        __builtin_amdgcn_s_setprio(0);
    };

    // ---- K-loop: 10 uniform 128-ch steps, 2-buffer counted-vmcnt, 2-deep A ----
    v8s aA[4], aB[4], bv[4];
    stage_t(0);
    loadA(0, 0, aA);
    loadA(0, 1, aB);
#pragma unroll
    for (int t = 0; t < NT; ++t) {
        // outstanding here: stage(t) x4 (oldest) + A(t,q0)+A(t,q1) x8 (newest)
        asm volatile("s_waitcnt vmcnt(8)" ::: "memory");
        __builtin_amdgcn_sched_barrier(0);
        __builtin_amdgcn_s_barrier();       // WAR: all waves done reading buf[(t+1)&1]
        __builtin_amdgcn_sched_barrier(0);
        if (t + 1 < NT) stage_t(t + 1);
        const char* bb = sbuf + (t & 1)*16384;
        dsread(bb, 0, bv); mf16(aA, bv); loadA(t, 2, aA);
        dsread(bb, 1, bv); mf16(aB, bv); loadA(t, 3, aB);
        dsread(bb, 2, bv); mf16(aA, bv); if (t + 1 < NT) loadA(t + 1, 0, aA);
        dsread(bb, 3, bv); mf16(aB, bv); if (t + 1 < NT) loadA(t + 1, 1, aB);
    }
    // buf1 now holds the center-tap tile == h_old (t=9 staged there, nothing after)

    // ---- gated activation -> sact LDS (buf0; all buf0 readers passed the t=9 barrier) ----
    char* sact = sbuf;
    const float* gb = gbias + layer*256;
#pragma unroll
    for (int mf = 0; mf < 4; ++mf) {
        int m0 = w*64 + mf*16 + lk*4;
        int c0 = m0 >> 1;                     // even
        float bF0 = gb[m0], bG0 = gb[m0+1], bF1 = gb[m0+2], bG1 = gb[m0+3];
#pragma unroll
        for (int nf = 0; nf < 4; ++nf) {
            int px = nf*16 + lrow;
            float o0 = gated(acc[mf][nf][0] + bF0, acc[mf][nf][1] + bG0);
            float o1 = gated(acc[mf][nf][2] + bF1, acc[mf][nf][3] + bG1);
            unsigned int pk = (unsigned int)f2bf(o0) | ((unsigned int)f2bf(o1) << 16);
            int byte = px*256 + c0*2;
            byte ^= (px & 7) << 4;
            *(unsigned int*)(sact + byte) = pk;
        }
    }
    // reuse acc as the res/skip accumulator
#pragma unroll
    for (int mf = 0; mf < 4; ++mf)
#pragma unroll
        for (int nf = 0; nf < 4; ++nf) acc[mf][nf] = (f32x4){0.f, 0.f, 0.f, 0.f};
    __syncthreads();

    // ---- res/skip 1x1 GEMM from sact ----
    const unsigned short* rwl = rw + (((size_t)layer*4*16) + w*4)*512 + lane*8;
#pragma unroll
    for (int q = 0; q < 4; ++q) {
        v8s av[4];
#pragma unroll
        for (int mf = 0; mf < 4; ++mf) av[mf] = *(const v8s*)(rwl + (size_t)(q*16 + mf)*512);
        dsread(sact, q, bv);
        __builtin_amdgcn_s_setprio(1);
#pragma unroll
        for (int mf = 0; mf < 4; ++mf)
#pragma unroll
            for (int nf = 0; nf < 4; ++nf)
                acc[mf][nf] = __builtin_amdgcn_mfma_f32_16x16x32_bf16(av[mf], bv[nf], acc[mf][nf], 0, 0, 0);
        __builtin_amdgcn_s_setprio(0);
    }

    // ---- read h_old pairs from buf1 (before sres overwrites it) ----
    unsigned int hold[4][4];
    if (layer < NL - 1) {
#pragma unroll
        for (int mf = 0; mf < 4; ++mf) {
            int c0 = w*32 + mf*8 + lk*2;
#pragma unroll
            for (int nf = 0; nf < 4; ++nf) {
                int px = nf*16 + lrow;
                int o = px*256 + ((c0*2) ^ ((px & 7) << 4));
                hold[mf][nf] = *(const unsigned int*)(sbuf + 16384 + o);
            }
        }
    }
    __syncthreads();                          // all sact/buf1 reads done before sres overwrite

    float* sresf = (float*)sbuf;              // f32 [128][64], 32 KB
    const int cp = tid >> 4, xg = tid & 15;
    const int pxl = tid & 63, cg = tid >> 6;

    if (layer < NL - 1) {
        // ---- transpose h_new = h_old + res + bias -> sres[c][px] (fp32) ----
#pragma unroll
        for (int mf = 0; mf < 4; ++mf) {
            int c0 = w*32 + mf*8 + lk*2;
            float bR0 = rbias[layer*256 + 2*c0];
            float bR1 = rbias[layer*256 + 2*(c0 + 1)];
#pragma unroll
            for (int nf = 0; nf < 4; ++nf) {
                int px = nf*16 + lrow;
                float h0 = bfu2f(hold[mf][nf] & 0xffffu);
                float h1 = __builtin_bit_cast(float, hold[mf][nf] & 0xffff0000u);
                sresf[(c0    )*PADF + px] = h0 + acc[mf][nf][0] + bR0;
                sresf[(c0 + 1)*PADF + px] = h1 + acc[mf][nf][2] + bR1;
            }
        }
        __syncthreads();
        // ---- bf16 pack h_new [px][c] -> hout (coalesced) ----
        {
            unsigned int pk3[16];
#pragma unroll
            for (int j = 0; j < 16; ++j) {
                float lo = sresf[(cg*32 + 2*j    )*PADF + pxl];
                float hi = sresf[(cg*32 + 2*j + 1)*PADF + pxl];
                pk3[j] = (unsigned int)f2bf(lo) | ((unsigned int)f2bf(hi) << 16);
            }
            unsigned short* hrow = hout + (((size_t)(b*HH + y))*WWP + x0 + pxl + PADW)*CCH + cg*32;
#pragma unroll
            for (int u = 0; u < 4; ++u)
                *(uint4*)(hrow + u*8) = make_uint4(pk3[u*4], pk3[u*4+1], pk3[u*4+2], pk3[u*4+3]);
        }
        __syncthreads();
    }

    // ---- skip half: transpose -> sres ----
#pragma unroll
    for (int mf = 0; mf < 4; ++mf) {
        int c0 = w*32 + mf*8 + lk*2;
#pragma unroll
        for (int nf = 0; nf < 4; ++nf) {
            int px = nf*16 + lrow;
            sresf[(c0    )*PADF + px] = acc[mf][nf][1];
            sresf[(c0 + 1)*PADF + px] = acc[mf][nf][3];
        }
    }
    __syncthreads();
    // ---- skip accumulate: layers 0-6 RMW bf16 skipbf; layer 7 writes fp32 d_out ----
#pragma unroll
    for (int it = 0; it < 8; ++it) {
        int cc = it*16 + cp;
        float4 s = *(float4*)(sresf + cc*PADF + xg*4);
        float bb2 = rbias[layer*256 + 2*cc + 1];
        s.x += bb2; s.y += bb2; s.z += bb2; s.w += bb2;
        size_t p = (((size_t)(b*CCH + cc))*HH + y)*WW + x0 + xg*4;
        if (layer == NL - 1) {
            uint2 o = *(const uint2*)(skipbf + p);
            float4 r;
            r.x = s.x + bfu2f(o.x & 0xffffu);
            r.y = s.y + bfu2f(o.x >> 16);
            r.z = s.z + bfu2f(o.y & 0xffffu);
            r.w = s.w + bfu2f(o.y >> 16);
            *(float4*)(outp + p) = r;
        } else {
            if (!first) {
                uint2 o = *(const uint2*)(skipbf + p);
                s.x += bfu2f(o.x & 0xffffu);
                s.y += bfu2f(o.x >> 16);
                s.z += bfu2f(o.y & 0xffffu);
                s.w += bfu2f(o.y >> 16);
            }
            uint2 np;
            np.x = (unsigned int)f2bf(s.x) | ((unsigned int)f2bf(s.y) << 16);
            np.y = (unsigned int)f2bf(s.z) | ((unsigned int)f2bf(s.w) << 16);
            *(uint2*)(skipbf + p) = np;
        }
    }
}

extern "C" void kernel_launch(void* const* d_in, const int* in_sizes, int n_in,
                              void* d_out, int out_size, void* d_ws, size_t ws_size,
                              hipStream_t stream) {
    const float* x       = (const float*)d_in[0];
    const float* c       = (const float*)d_in[1];
    const float* front_w = (const float*)d_in[2];
    const float* front_b = (const float*)d_in[3];
    const float* fg_w    = (const float*)d_in[4];
    const float* fg_b    = (const float*)d_in[5];
    const float* fgc_w   = (const float*)d_in[6];
    const float* fgc_b   = (const float*)d_in[7];
    const float* rs_w    = (const float*)d_in[8];
    const float* rs_b    = (const float*)d_in[9];

    char* ws = (char*)d_ws;
    unsigned short* hbf0 = (unsigned short*)ws;     ws += (size_t)HBF_N * 2;
    unsigned short* hbf1 = (unsigned short*)ws;     ws += (size_t)HBF_N * 2;
    unsigned short* zrow = (unsigned short*)ws;     ws += (size_t)ZROW_N * 2;
    unsigned short* cT   = (unsigned short*)ws;     ws += (size_t)CT_N * 2;
    unsigned short* skbf = (unsigned short*)ws;     ws += (size_t)SKB_N * 2;
    unsigned short* gw   = (unsigned short*)ws;     ws += (size_t)GW_N * 2;
    unsigned short* rwq  = (unsigned short*)ws;     ws += (size_t)RW_N * 2;
    float* gbias  = (float*)ws;                     ws += (size_t)NL * 256 * 4;
    float* rbias  = (float*)ws;

    float* outp = (float*)d_out;

    prep_weights<<<2048, 256, 0, stream>>>(fg_w, fgc_w, rs_w, fg_b, fgc_b, rs_b,
                                           gw, rwq, gbias, rbias);
    front_kernel<<<2048, 256, 0, stream>>>(x, front_w, front_b, hbf0, hbf1, zrow);
    cond_transpose<<<dim3(64, 16, 2), 256, 0, stream>>>(c, cT);

    static const int DILH[NL] = {1, 2, 4, 8, 1, 2, 4, 8};
    static const int DILW[NL] = {1, 2, 4, 8, 16, 32, 64, 128};

    for (int i = 0; i < NL; ++i) {
        const unsigned short* hin = (i & 1) ? hbf1 : hbf0;
        unsigned short*       hout= (i & 1) ? hbf0 : hbf1;
        layer_fused<<<dim3(64, 16, 2), 256, 0, stream>>>(hin, hout, zrow, cT, gw, gbias,
                                                         rwq, rbias, skbf, outp,
                                                         i, DILH[i], DILW[i], i == 0 ? 1 : 0);
    }
}